// Round 10
// baseline (221.555 us; speedup 1.0000x reference)
//
#include <hip/hip_runtime.h>
#include <cstdint>

typedef unsigned long long u64;
typedef unsigned int u32;

#define WPRE 400
#define MIN_SCORE 0.01f
#define MAX_OVERLAP 0.45f
#define INV32 0x407FFFFFu   // f32_key(-1.0f)

// Exact predicate: fdiv_rn(inter,uniC) > 0.45f  <=>  (double)inter > MID*(double)uniC
// MID = midpoint(0.45f, nextafterf(0.45f,+inf)) = 0x1.CCCCCDp-2 (exact double).
#define IOU_MID 0x1.CCCCCDp-2

__device__ __forceinline__ u32 f32_key(float f) {
    u32 u = __float_as_uint(f);
    return (f >= 0.0f) ? (u | 0x80000000u) : ~u;
}
__device__ __forceinline__ float key_f32(u32 k) {
    return __uint_as_float((k & 0x80000000u) ? (k ^ 0x80000000u) : ~k);
}

struct SelSt {
    u64 prefix, thr;
    int r, above, shift, nge, done;
    u32 wtot[8];
};

// Exact top-K threshold over unique u64 keys (descending) via 1024-bin
// histogram level-descent. On return: st->thr such that
// count(keys >= thr) == st->nge, K <= nge <= CAP. Keys must be unique.
// bulk: a key value whose bits [63:14] are shared by a large clump of keys
// (they are register-counted, one LDS atomic per wave per pass); 0 disables.
template <int T, typename KF>
__device__ void hist_select64(KF kf, int N, int K, int CAP, u64 bulk,
                              int tid, u32* hist, SelSt* st)
{
    const int lane = tid & 63;
    const int wv = tid >> 6;
    const int nw = T >> 6;
    constexpr int BPT = 1024 / T;

    if (tid == 0) { st->prefix = 0ull; st->r = K; st->above = 0; st->shift = 54; st->done = 0; }
    __syncthreads();

    while (true) {
        const int shift = st->shift;
        const u64 pref = st->prefix;
        const int r = st->r;
        const int above = st->above;
        const bool lvl0 = (shift == 54);
        #pragma unroll
        for (int q = 0; q < BPT; ++q) hist[tid * BPT + q] = 0u;
        __syncthreads();

        const bool useBulk = (bulk != 0ull) && (shift >= 14);
        const u64 bulkHi = bulk >> 14;
        u32 bulkCnt = 0;
        for (int i = tid; i < N; i += T) {
            u64 k;
            if (!kf(i, k)) continue;
            if (!lvl0 && (k >> (shift + 10)) != pref) continue;
            if (useBulk && (k >> 14) == bulkHi) { ++bulkCnt; continue; }
            atomicAdd(&hist[(u32)(k >> shift) & 1023u], 1u);
        }
        if (useBulk) {
            #pragma unroll
            for (int off = 32; off > 0; off >>= 1) bulkCnt += __shfl_down(bulkCnt, off, 64);
            if (lane == 0 && bulkCnt) atomicAdd(&hist[(u32)(bulk >> shift) & 1023u], bulkCnt);
        }
        __syncthreads();

        // block suffix-scan over 1024 bins (thread t owns bins [t*BPT, ...))
        u32 hloc[BPT], Sarr[BPT];
        u32 run = 0;
        #pragma unroll
        for (int q = BPT - 1; q >= 0; --q) {
            hloc[q] = hist[tid * BPT + q];
            run += hloc[q];
            Sarr[q] = run;
        }
        u32 incl = run;
        #pragma unroll
        for (int off = 1; off < 64; off <<= 1) {
            u32 x = __shfl_down(incl, off, 64);
            incl += (lane + off < 64) ? x : 0u;
        }
        if (lane == 0) st->wtot[wv] = incl;
        __syncthreads();
        u32 wa = 0;
        for (int w2 = wv + 1; w2 < nw; ++w2) wa += st->wtot[w2];
        const u32 suffAbove = wa + (incl - run);

        bool found = false; int fb = 0; u32 fSn = 0, fh = 0;
        #pragma unroll
        for (int q = 0; q < BPT; ++q) {
            u32 S = suffAbove + Sarr[q];
            u32 Sn = S - hloc[q];
            if ((int)S >= r && (int)Sn < r) { found = true; fb = tid * BPT + q; fSn = Sn; fh = hloc[q]; }
        }
        __syncthreads();
        if (found) {
            u64 np = (pref << 10) | (u64)(u32)fb;
            int nab = above + (int)fSn;
            int nge = nab + (int)fh;
            st->prefix = np;
            st->r = r - (int)fSn;
            st->above = nab;
            st->nge = nge;
            st->thr = np << shift;
            st->shift = shift - 10;
            st->done = (nge <= CAP) || (shift == 4);
        }
        __syncthreads();
        if (st->done) break;
    }
}

// ---------------- Kernel 1: decode boxes + softmax ----------------
__global__ __launch_bounds__(256) void decode_softmax_kernel(
    const float* __restrict__ locs, const float* __restrict__ scores,
    const float* __restrict__ priors, float* __restrict__ dec,
    float* __restrict__ probs_t, int P, int C, int NC)
{
    __shared__ float tile[64 * 81];
    __shared__ float mrow[64], srow[64];
    const int b  = blockIdx.y;
    const int p0 = blockIdx.x * 64;
    const int tid = threadIdx.x;
    const int nrows = min(64, P - p0);
    const int n = nrows * C;

    const float* src = scores + ((size_t)b * P + p0) * C;
    for (int idx = tid; idx < n; idx += 256) tile[idx] = src[idx];

    if (tid < nrows) {
        int p = p0 + tid;
        float4 lc = ((const float4*)locs)[(size_t)b * P + p];
        float4 pr = ((const float4*)priors)[p];
        float cx = lc.x * pr.z / 10.0f + pr.x;
        float cy = lc.y * pr.w / 10.0f + pr.y;
        float w  = expf(lc.z / 5.0f) * pr.z;
        float h  = expf(lc.w / 5.0f) * pr.w;
        ((float4*)dec)[(size_t)b * P + p] =
            make_float4(cx - w * 0.5f, cy - h * 0.5f, cx + w * 0.5f, cy + h * 0.5f);
    }
    __syncthreads();

    if (tid < nrows) {
        const float* row = &tile[tid * C];
        float m = row[0];
        for (int cc = 1; cc < C; ++cc) m = fmaxf(m, row[cc]);
        float ss = 0.f;
        for (int cc = 0; cc < C; ++cc) ss += expf(row[cc] - m);
        mrow[tid] = m; srow[tid] = ss;
    }
    __syncthreads();

    for (int idx = tid; idx < 64 * NC; idx += 256) {
        int r  = idx & 63;
        int cc = idx >> 6;
        if (r < nrows) {
            float v = expf(tile[r * C + cc + 1] - mrow[r]) / srow[r];
            probs_t[((size_t)(b * NC + cc)) * P + p0 + r] = v;
        }
    }
}

// exact IoU predicate vs column box (bi, ai wave-uniform; same op order as ref)
#define IOU_PRED(bjv, ajv, prv) \
    { float lx = fmaxf(bi.x, (bjv).x); float ly = fmaxf(bi.y, (bjv).y); \
      float rx = fminf(bi.z, (bjv).z); float ry = fminf(bi.w, (bjv).w); \
      float ww = fmaxf(rx - lx, 0.f);  float hh = fmaxf(ry - ly, 0.f); \
      float inter = ww * hh; \
      float uniC = fmaxf((ai + (ajv)) - inter, 1e-10f); \
      prv = (double)inter > IOU_MID * (double)uniC; }

// ------- Kernel 2: fused per (class,image) top-400 select + sort + IoU + NMS scan -------
__global__ __launch_bounds__(512) void select_nms_kernel(
    const float* __restrict__ dec, const float* __restrict__ probs_t,
    float* __restrict__ cand_sc, float* __restrict__ cand_bx,
    int P, int NC)
{
    const int c = blockIdx.x, b = blockIdx.y;
    const int tid = threadIdx.x;
    const int lane = tid & 63;
    const int wv = tid >> 6;
    const int T = 512;

    // skey (34944 B) is dead after compaction; inw (25088 B) aliases it.
    __shared__ alignas(16) char bufA[8736 * 4];
    u32* skey = (u32*)bufA;
    u64* inw  = (u64*)bufA;             // [w][r][lane] column words
    __shared__ u64 cand[512];           // hist[1024] aliases cand (dead until compaction)
    u32* hist = (u32*)cand;
    __shared__ float4 cbox[448];
    __shared__ float ara[448];
    __shared__ u64 validm[7], keepm[7];
    __shared__ SelSt st;
    __shared__ int sh_cnt;

    const float* ps = probs_t + ((size_t)(b * NC + c)) * P;

    // ---- stage masked sortable keys to LDS (vectorized) ----
    int P4 = P >> 2;
    for (int i = tid; i < P4; i += T) {
        float4 f4 = ((const float4*)ps)[i];
        skey[i*4+0] = f32_key(f4.x > MIN_SCORE ? f4.x : -1.0f);
        skey[i*4+1] = f32_key(f4.y > MIN_SCORE ? f4.y : -1.0f);
        skey[i*4+2] = f32_key(f4.z > MIN_SCORE ? f4.z : -1.0f);
        skey[i*4+3] = f32_key(f4.w > MIN_SCORE ? f4.w : -1.0f);
    }
    for (int i = (P4 << 2) + tid; i < P; i += T) {
        float f = ps[i];
        skey[i] = f32_key(f > MIN_SCORE ? f : -1.0f);
    }
    if (tid == 0) sh_cnt = 0;
    __syncthreads();

    // ---- exact top-400 threshold ----
    hist_select64<512>([&](int i, u64& k) {
                           k = ((u64)skey[i] << 32) | (u64)(u32)(~(u32)i);
                           return true;
                       },
                       P, WPRE, 512, ((u64)INV32) << 32, tid, hist, &st);
    const u64 thr = st.thr;

    // ---- compact keys >= thr (count == st.nge <= 512) ----
    for (int i = tid; i < P; i += T) {
        u64 k = ((u64)skey[i] << 32) | (u64)(u32)(~(u32)i);
        if (k >= thr) {
            int pos = atomicAdd(&sh_cnt, 1);
            if (pos < 512) cand[pos] = k;
        }
    }
    __syncthreads();                    // last read of skey is above
    const int cnt = sh_cnt;             // in [400, 512]
    u64 v = (tid < cnt) ? cand[tid] : 0ull;

    // ---- register bitonic sort 512 desc: shfl within wave, LDS for j>=64 ----
    for (int k = 2; k <= 512; k <<= 1) {
        for (int j = k >> 1; j > 0; j >>= 1) {
            u64 p;
            if (j < 64) {
                p = __shfl_xor(v, j, 64);
            } else {
                __syncthreads();
                cand[tid] = v;
                __syncthreads();
                p = cand[tid ^ j];
            }
            bool takeMax = (((tid & k) == 0) == ((tid & j) == 0));
            v = takeMax ? (v > p ? v : p) : (v > p ? p : v);
        }
    }
    __syncthreads();

    // ---- unpack rank-tid candidate into SoA; slots 400..447 zero-pad ----
    float4 mybox = make_float4(0.f, 0.f, 0.f, 0.f);
    float myval = -1.0f;
    if (tid < 448) {
        if (tid < WPRE) {
            myval = key_f32((u32)(v >> 32));
            int p = (int)(~(u32)v);
            mybox = ((const float4*)dec)[(size_t)b * P + p];
        }
        cbox[tid] = mybox;
        ara[tid] = (mybox.z - mybox.x) * (mybox.w - mybox.y);
        u64 mk = __ballot(myval > MIN_SCORE);
        if (lane == 0) validm[tid >> 6] = mk;
    }
    __syncthreads();   // skey region now safe to overwrite as inw

    // ---- column-register IoU matrix: k2-outer, rows read once per wave-chunk ----
    // 28 upper-triangle tiles partitioned contiguously over 8 waves; each chunk
    // holds <=4 column blocks (bj) in registers, rows broadcast-read once.
    {
        const int t0 = (28 * wv) >> 3;
        const int t1 = (28 * (wv + 1)) >> 3;
        int t = t0;
        while (t < t1) {
            int r = 0, S = 0;
            while (t - S >= 7 - r) { S += 7 - r; ++r; }
            const int w0c = r + (t - S);
            const int wc = min(t1 - t, 7 - w0c);       // 1..4, wave-uniform
            float4 bj0 = cbox[((w0c + 0) << 6) + lane];
            float  aj0 = ara [((w0c + 0) << 6) + lane];
            float4 bj1 = bj0; float aj1 = aj0;
            float4 bj2 = bj0; float aj2 = aj0;
            float4 bj3 = bj0; float aj3 = aj0;
            if (wc > 1) { bj1 = cbox[((w0c + 1) << 6) + lane]; aj1 = ara[((w0c + 1) << 6) + lane]; }
            if (wc > 2) { bj2 = cbox[((w0c + 2) << 6) + lane]; aj2 = ara[((w0c + 2) << 6) + lane]; }
            if (wc > 3) { bj3 = cbox[((w0c + 3) << 6) + lane]; aj3 = ara[((w0c + 3) << 6) + lane]; }
            u32 l0 = 0, h0 = 0, l1 = 0, h1 = 0, l2 = 0, h2 = 0, l3 = 0, h3 = 0;
            const int i0 = r << 6;
            #pragma unroll 8
            for (int k2 = 0; k2 < 64; ++k2) {
                float4 bi = cbox[i0 + k2];       // wave-uniform broadcast
                float  ai = ara [i0 + k2];
                u32 bit = 1u << (k2 & 31);
                bool p0, p1, p2, p3;
                IOU_PRED(bj0, aj0, p0);
                if (p0) { if (k2 < 32) l0 |= bit; else h0 |= bit; }
                if (wc > 1) {
                    IOU_PRED(bj1, aj1, p1);
                    if (p1) { if (k2 < 32) l1 |= bit; else h1 |= bit; }
                }
                if (wc > 2) {
                    IOU_PRED(bj2, aj2, p2);
                    if (p2) { if (k2 < 32) l2 |= bit; else h2 |= bit; }
                }
                if (wc > 3) {
                    IOU_PRED(bj3, aj3, p3);
                    if (p3) { if (k2 < 32) l3 |= bit; else h3 |= bit; }
                }
            }
            inw[((w0c + 0) * 7 + r) * 64 + lane] = ((u64)h0 << 32) | l0;
            if (wc > 1) inw[((w0c + 1) * 7 + r) * 64 + lane] = ((u64)h1 << 32) | l1;
            if (wc > 2) inw[((w0c + 2) * 7 + r) * 64 + lane] = ((u64)h2 << 32) | l2;
            if (wc > 3) inw[((w0c + 3) * 7 + r) * 64 + lane] = ((u64)h3 << 32) | l3;
            t += wc;
        }
    }
    __syncthreads();

    // ---- single-wave hierarchical scan, zero barriers inside ----
    if (wv == 0) {
        u64 keep[7];
        #pragma unroll
        for (int w2 = 0; w2 < 7; ++w2) {
            bool alive = ((validm[w2] >> lane) & 1ull) != 0;
            #pragma unroll
            for (int r = 0; r < w2; ++r) {
                u64 inr = inw[(w2 * 7 + r) * 64 + lane];
                alive = alive && ((inr & keep[r]) == 0ull);
            }
            u64 in_self = inw[(w2 * 7 + w2) * 64 + lane];
            u64 inmask = in_self & ((1ull << lane) - 1ull);   // only t < lane matter
            u64 mm = inmask;
            #pragma unroll
            for (int off = 32; off; off >>= 1) mm |= __shfl_xor(mm, off, 64);
            while (mm) {                        // iterate only suppressing rows
                int t = __builtin_ctzll(mm);
                mm &= mm - 1ull;
                u64 am = __ballot(alive);
                if ((am >> t) & 1ull)
                    alive = alive && (((inmask >> t) & 1ull) == 0ull);
            }
            u64 fin = __ballot(alive);
            keep[w2] = fin;
            if (lane == 0) keepm[w2] = fin;
        }
    }
    __syncthreads();

    if (tid < WPRE) {
        bool keep = (keepm[tid >> 6] >> (tid & 63)) & 1ull;
        cand_sc[((size_t)(b * NC + c)) * WPRE + tid] = keep ? myval : -1.0f;
        ((float4*)cand_bx)[((size_t)(b * NC + c)) * WPRE + tid] = mybox;
    }
}

// ---------------- Kernel 3a: per (image, class-group) exact top-200 ----------------
__global__ __launch_bounds__(512) void topkA_kernel(
    const float* __restrict__ cand_sc, u64* __restrict__ wsA,
    int NC, int TOPK, int GS, int NG)
{
    const int g = blockIdx.x, b = blockIdx.y;
    const int tid = threadIdx.x;
    const int T = 512;
    const int N = GS;                 // 3200
    const u32 fbase = (u32)(g * GS);

    __shared__ u32 hist[1024];
    __shared__ SelSt st;
    __shared__ int sh_cnt;

    const float* s = cand_sc + (size_t)b * NC * WPRE + (size_t)g * GS;
    u64* outg = wsA + (size_t)(b * NG + g) * 256;

    if (tid == 0) sh_cnt = 0;
    __syncthreads();

    hist_select64<512>([&](int i, u64& k) {
                           k = ((u64)f32_key(s[i]) << 32) | (u64)(u32)(~(fbase + (u32)i));
                           return true;
                       },
                       N, TOPK, 256, ((u64)INV32) << 32, tid, hist, &st);
    const u64 thr = st.thr;

    for (int i = tid; i < N; i += T) {
        u64 k = ((u64)f32_key(s[i]) << 32) | (u64)(u32)(~(fbase + (u32)i));
        if (k >= thr) {
            int pos = atomicAdd(&sh_cnt, 1);
            if (pos < 256) outg[pos] = k;
        }
    }
    __syncthreads();
    int cnt = sh_cnt;   // in [TOPK, 256]
    if (tid < 256 && tid >= cnt) outg[tid] = 0ull;
}

// ---------------- Kernel 3b: merge groups, exact top-200, emit ----------------
__global__ __launch_bounds__(256) void topkB_kernel(
    const u64* __restrict__ wsA, const float* __restrict__ cand_bx,
    float* __restrict__ out, int NC, int TOPK, int B, int NG)
{
    const int b = blockIdx.x;
    const int tid = threadIdx.x;
    const int T = 256;
    const int N = NG * 256;           // 2560

    __shared__ u64 keys[2560];
    __shared__ u32 hist[1024];        // cand[256] aliases hist (dead at compaction)
    u64* cand = (u64*)hist;
    __shared__ SelSt st;
    __shared__ int sh_cnt;

    const u64* src = wsA + (size_t)b * N;
    for (int i = tid; i < N; i += T) keys[i] = src[i];
    if (tid == 0) sh_cnt = 0;
    __syncthreads();

    hist_select64<256>([&](int i, u64& k) { k = keys[i]; return true; },
                       N, TOPK, 256, ((u64)INV32) << 32, tid, hist, &st);
    const u64 thr = st.thr;

    for (int i = tid; i < N; i += T) {
        u64 k = keys[i];
        if (k >= thr) {
            int pos = atomicAdd(&sh_cnt, 1);
            if (pos < 256) cand[pos] = k;
        }
    }
    __syncthreads();
    int cnt = sh_cnt;
    u64 v = (tid < cnt) ? cand[tid] : 0ull;

    // register bitonic sort 256 desc (full u64 -> exact (score, flat) order)
    for (int k = 2; k <= 256; k <<= 1) {
        for (int j = k >> 1; j > 0; j >>= 1) {
            u64 p;
            if (j < 64) {
                p = __shfl_xor(v, j, 64);
            } else {
                __syncthreads();
                cand[tid] = v;
                __syncthreads();
                p = cand[tid ^ j];
            }
            bool takeMax = (((tid & k) == 0) == ((tid & j) == 0));
            v = takeMax ? (v > p ? v : p) : (v > p ? p : v);
        }
    }

    if (tid < TOPK) {
        float sc = key_f32((u32)(v >> 32));
        int flat = (int)(~(u32)v);
        int cls = flat / WPRE;
        float4 bx = ((const float4*)cand_bx)[(size_t)b * NC * WPRE + flat];
        float* ob = out + ((size_t)(b * TOPK + tid)) * 4;
        ob[0] = bx.x; ob[1] = bx.y; ob[2] = bx.z; ob[3] = bx.w;
        out[(size_t)B * TOPK * 4 + (size_t)b * TOPK + tid] = (float)(cls + 1);
        out[(size_t)B * TOPK * 5 + (size_t)b * TOPK + tid] = sc;
    }
}

extern "C" void kernel_launch(void* const* d_in, const int* in_sizes, int n_in,
                              void* d_out, int out_size, void* d_ws, size_t ws_size,
                              hipStream_t stream) {
    const float* locs   = (const float*)d_in[0];
    const float* scores = (const float*)d_in[1];
    const float* priors = (const float*)d_in[2];

    const int P  = in_sizes[2] / 4;          // 8732
    const int B  = in_sizes[0] / (4 * P);    // 8
    const int C  = in_sizes[1] / (B * P);    // 81
    const int NC = C - 1;                    // 80
    const int TOPK = out_size / (B * 6);     // 200
    const int NG = 10;                       // class groups per image
    const int GS = (NC * WPRE) / NG;         // 3200 entries per group

    float* ws      = (float*)d_ws;
    float* dec     = ws;                                    // B*P*4
    float* probs_t = dec + (size_t)B * P * 4;               // B*NC*P
    float* cand_sc = probs_t + (size_t)B * NC * P;          // B*NC*WPRE
    float* cand_bx = cand_sc + (size_t)B * NC * WPRE;       // B*NC*WPRE*4
    u64*   wsA     = (u64*)(cand_bx + (size_t)B * NC * WPRE * 4);  // B*NG*256 u64

    dim3 g1((P + 63) / 64, B);
    decode_softmax_kernel<<<g1, 256, 0, stream>>>(locs, scores, priors, dec, probs_t, P, C, NC);

    dim3 g2(NC, B);
    select_nms_kernel<<<g2, 512, 0, stream>>>(dec, probs_t, cand_sc, cand_bx, P, NC);

    dim3 g3(NG, B);
    topkA_kernel<<<g3, 512, 0, stream>>>(cand_sc, wsA, NC, TOPK, GS, NG);
    topkB_kernel<<<dim3(B), 256, 0, stream>>>(wsA, cand_bx, (float*)d_out, NC, TOPK, B, NG);
}

// Round 11
// 171.844 us; speedup vs baseline: 1.2893x; 1.2893x over previous
//
#include <hip/hip_runtime.h>
#include <cstdint>

typedef unsigned long long u64;
typedef unsigned int u32;

#define WPRE 400
#define MIN_SCORE 0.01f
#define MAX_OVERLAP 0.45f
#define INV32 0x407FFFFFu   // f32_key(-1.0f)

// Exact predicate: fdiv_rn(inter,uniC) > 0.45f  <=>  (double)inter > MID*(double)uniC
// MID = midpoint(0.45f, nextafterf(0.45f,+inf)) = 0x1.CCCCCDp-2 (exact double).
#define IOU_MID 0x1.CCCCCDp-2

__device__ __forceinline__ u32 f32_key(float f) {
    u32 u = __float_as_uint(f);
    return (f >= 0.0f) ? (u | 0x80000000u) : ~u;
}
__device__ __forceinline__ float key_f32(u32 k) {
    return __uint_as_float((k & 0x80000000u) ? (k ^ 0x80000000u) : ~k);
}

struct SelSt {
    u64 prefix, thr;
    int r, above, shift, nge, done;
    u32 wtot[8];
};

// Exact top-K threshold over unique u64 keys (descending) via 1024-bin
// histogram level-descent. On return: st->thr such that
// count(keys >= thr) == st->nge, K <= nge <= CAP. Keys must be unique.
// bulk: a key value whose bits [63:14] are shared by a large clump of keys
// (they are register-counted, one LDS atomic per wave per pass); 0 disables.
template <int T, typename KF>
__device__ void hist_select64(KF kf, int N, int K, int CAP, u64 bulk,
                              int tid, u32* hist, SelSt* st)
{
    const int lane = tid & 63;
    const int wv = tid >> 6;
    const int nw = T >> 6;
    constexpr int BPT = 1024 / T;

    if (tid == 0) { st->prefix = 0ull; st->r = K; st->above = 0; st->shift = 54; st->done = 0; }
    __syncthreads();

    while (true) {
        const int shift = st->shift;
        const u64 pref = st->prefix;
        const int r = st->r;
        const int above = st->above;
        const bool lvl0 = (shift == 54);
        #pragma unroll
        for (int q = 0; q < BPT; ++q) hist[tid * BPT + q] = 0u;
        __syncthreads();

        const bool useBulk = (bulk != 0ull) && (shift >= 14);
        const u64 bulkHi = bulk >> 14;
        u32 bulkCnt = 0;
        for (int i = tid; i < N; i += T) {
            u64 k;
            if (!kf(i, k)) continue;
            if (!lvl0 && (k >> (shift + 10)) != pref) continue;
            if (useBulk && (k >> 14) == bulkHi) { ++bulkCnt; continue; }
            atomicAdd(&hist[(u32)(k >> shift) & 1023u], 1u);
        }
        if (useBulk) {
            #pragma unroll
            for (int off = 32; off > 0; off >>= 1) bulkCnt += __shfl_down(bulkCnt, off, 64);
            if (lane == 0 && bulkCnt) atomicAdd(&hist[(u32)(bulk >> shift) & 1023u], bulkCnt);
        }
        __syncthreads();

        // block suffix-scan over 1024 bins (thread t owns bins [t*BPT, ...))
        u32 hloc[BPT], Sarr[BPT];
        u32 run = 0;
        #pragma unroll
        for (int q = BPT - 1; q >= 0; --q) {
            hloc[q] = hist[tid * BPT + q];
            run += hloc[q];
            Sarr[q] = run;
        }
        u32 incl = run;
        #pragma unroll
        for (int off = 1; off < 64; off <<= 1) {
            u32 x = __shfl_down(incl, off, 64);
            incl += (lane + off < 64) ? x : 0u;
        }
        if (lane == 0) st->wtot[wv] = incl;
        __syncthreads();
        u32 wa = 0;
        for (int w2 = wv + 1; w2 < nw; ++w2) wa += st->wtot[w2];
        const u32 suffAbove = wa + (incl - run);

        bool found = false; int fb = 0; u32 fSn = 0, fh = 0;
        #pragma unroll
        for (int q = 0; q < BPT; ++q) {
            u32 S = suffAbove + Sarr[q];
            u32 Sn = S - hloc[q];
            if ((int)S >= r && (int)Sn < r) { found = true; fb = tid * BPT + q; fSn = Sn; fh = hloc[q]; }
        }
        __syncthreads();
        if (found) {
            u64 np = (pref << 10) | (u64)(u32)fb;
            int nab = above + (int)fSn;
            int nge = nab + (int)fh;
            st->prefix = np;
            st->r = r - (int)fSn;
            st->above = nab;
            st->nge = nge;
            st->thr = np << shift;
            st->shift = shift - 10;
            st->done = (nge <= CAP) || (shift == 4);
        }
        __syncthreads();
        if (st->done) break;
    }
}

// ---------------- Kernel 1: decode boxes + softmax ----------------
__global__ __launch_bounds__(256) void decode_softmax_kernel(
    const float* __restrict__ locs, const float* __restrict__ scores,
    const float* __restrict__ priors, float* __restrict__ dec,
    float* __restrict__ probs_t, int P, int C, int NC)
{
    __shared__ float tile[64 * 81];
    __shared__ float mrow[64], srow[64];
    const int b  = blockIdx.y;
    const int p0 = blockIdx.x * 64;
    const int tid = threadIdx.x;
    const int nrows = min(64, P - p0);
    const int n = nrows * C;

    const float* src = scores + ((size_t)b * P + p0) * C;
    for (int idx = tid; idx < n; idx += 256) tile[idx] = src[idx];

    if (tid < nrows) {
        int p = p0 + tid;
        float4 lc = ((const float4*)locs)[(size_t)b * P + p];
        float4 pr = ((const float4*)priors)[p];
        float cx = lc.x * pr.z / 10.0f + pr.x;
        float cy = lc.y * pr.w / 10.0f + pr.y;
        float w  = expf(lc.z / 5.0f) * pr.z;
        float h  = expf(lc.w / 5.0f) * pr.w;
        ((float4*)dec)[(size_t)b * P + p] =
            make_float4(cx - w * 0.5f, cy - h * 0.5f, cx + w * 0.5f, cy + h * 0.5f);
    }
    __syncthreads();

    if (tid < nrows) {
        const float* row = &tile[tid * C];
        float m = row[0];
        for (int cc = 1; cc < C; ++cc) m = fmaxf(m, row[cc]);
        float ss = 0.f;
        for (int cc = 0; cc < C; ++cc) ss += expf(row[cc] - m);
        mrow[tid] = m; srow[tid] = ss;
    }
    __syncthreads();

    for (int idx = tid; idx < 64 * NC; idx += 256) {
        int r  = idx & 63;
        int cc = idx >> 6;
        if (r < nrows) {
            float v = expf(tile[r * C + cc + 1] - mrow[r]) / srow[r];
            probs_t[((size_t)(b * NC + cc)) * P + p0 + r] = v;
        }
    }
}

// exact IoU predicate vs column box (bi, ai wave-uniform; same op order as ref)
#define IOU_PRED(bjv, ajv, prv) \
    { float lx = fmaxf(bi.x, (bjv).x); float ly = fmaxf(bi.y, (bjv).y); \
      float rx = fminf(bi.z, (bjv).z); float ry = fminf(bi.w, (bjv).w); \
      float ww = fmaxf(rx - lx, 0.f);  float hh = fmaxf(ry - ly, 0.f); \
      float inter = ww * hh; \
      float uniC = fmaxf((ai + (ajv)) - inter, 1e-10f); \
      prv = (double)inter > IOU_MID * (double)uniC; }

// One (or a statically-paired two) 64x64 IoU tile(s) sharing row block r.
// Fully static: compile-time PAIR, compile-time bit constants, no branches
// inside the unrolled loops (round-10 lesson: dynamic variants wreck codegen).
template <bool PAIR>
__device__ __forceinline__ void iou_tile2(
    const float4* cbox, const float* ara, u64* inw,
    int r, int wA, int wB, int lane)
{
    float4 bjA = cbox[(wA << 6) + lane];
    float  ajA = ara [(wA << 6) + lane];
    float4 bjB = bjA; float ajB = ajA;
    if (PAIR) { bjB = cbox[(wB << 6) + lane]; ajB = ara[(wB << 6) + lane]; }
    u32 lA = 0u, hA = 0u, lB = 0u, hB = 0u;
    const int i0 = r << 6;
    #pragma unroll 16
    for (int q = 0; q < 32; ++q) {
        float4 bi = cbox[i0 + q];        // wave-uniform broadcast, read once
        float  ai = ara [i0 + q];
        bool pA; IOU_PRED(bjA, ajA, pA);
        lA |= pA ? (1u << q) : 0u;
        if (PAIR) { bool pB; IOU_PRED(bjB, ajB, pB); lB |= pB ? (1u << q) : 0u; }
    }
    #pragma unroll 16
    for (int q = 0; q < 32; ++q) {
        float4 bi = cbox[i0 + 32 + q];
        float  ai = ara [i0 + 32 + q];
        bool pA; IOU_PRED(bjA, ajA, pA);
        hA |= pA ? (1u << q) : 0u;
        if (PAIR) { bool pB; IOU_PRED(bjB, ajB, pB); hB |= pB ? (1u << q) : 0u; }
    }
    inw[(wA * 7 + r) * 64 + lane] = ((u64)hA << 32) | lA;
    if (PAIR) inw[(wB * 7 + r) * 64 + lane] = ((u64)hB << 32) | lB;
}

// ------- Kernel 2: fused per (class,image) top-400 select + sort + IoU + NMS scan -------
__global__ __launch_bounds__(512) void select_nms_kernel(
    const float* __restrict__ dec, const float* __restrict__ probs_t,
    float* __restrict__ cand_sc, float* __restrict__ cand_bx,
    int P, int NC)
{
    const int c = blockIdx.x, b = blockIdx.y;
    const int tid = threadIdx.x;
    const int lane = tid & 63;
    const int wv = tid >> 6;
    const int T = 512;

    // skey (34944 B) is dead after compaction; inw (25088 B) aliases it.
    __shared__ alignas(16) char bufA[8736 * 4];
    u32* skey = (u32*)bufA;
    u64* inw  = (u64*)bufA;             // [w][r][lane] column words
    __shared__ u64 cand[512];           // hist[1024] aliases cand (dead until compaction)
    u32* hist = (u32*)cand;
    __shared__ float4 cbox[448];
    __shared__ float ara[448];
    __shared__ u64 validm[7], keepm[7];
    __shared__ SelSt st;
    __shared__ int sh_cnt;

    const float* ps = probs_t + ((size_t)(b * NC + c)) * P;

    // ---- stage masked sortable keys to LDS (vectorized) ----
    int P4 = P >> 2;
    for (int i = tid; i < P4; i += T) {
        float4 f4 = ((const float4*)ps)[i];
        skey[i*4+0] = f32_key(f4.x > MIN_SCORE ? f4.x : -1.0f);
        skey[i*4+1] = f32_key(f4.y > MIN_SCORE ? f4.y : -1.0f);
        skey[i*4+2] = f32_key(f4.z > MIN_SCORE ? f4.z : -1.0f);
        skey[i*4+3] = f32_key(f4.w > MIN_SCORE ? f4.w : -1.0f);
    }
    for (int i = (P4 << 2) + tid; i < P; i += T) {
        float f = ps[i];
        skey[i] = f32_key(f > MIN_SCORE ? f : -1.0f);
    }
    if (tid == 0) sh_cnt = 0;
    __syncthreads();

    // ---- exact top-400 threshold ----
    hist_select64<512>([&](int i, u64& k) {
                           k = ((u64)skey[i] << 32) | (u64)(u32)(~(u32)i);
                           return true;
                       },
                       P, WPRE, 512, ((u64)INV32) << 32, tid, hist, &st);
    const u64 thr = st.thr;

    // ---- compact keys >= thr (count == st.nge <= 512) ----
    for (int i = tid; i < P; i += T) {
        u64 k = ((u64)skey[i] << 32) | (u64)(u32)(~(u32)i);
        if (k >= thr) {
            int pos = atomicAdd(&sh_cnt, 1);
            if (pos < 512) cand[pos] = k;
        }
    }
    __syncthreads();                    // last read of skey is above
    const int cnt = sh_cnt;             // in [400, 512]
    u64 v = (tid < cnt) ? cand[tid] : 0ull;

    // ---- register bitonic sort 512 desc: shfl within wave, LDS for j>=64 ----
    for (int k = 2; k <= 512; k <<= 1) {
        for (int j = k >> 1; j > 0; j >>= 1) {
            u64 p;
            if (j < 64) {
                p = __shfl_xor(v, j, 64);
            } else {
                __syncthreads();
                cand[tid] = v;
                __syncthreads();
                p = cand[tid ^ j];
            }
            bool takeMax = (((tid & k) == 0) == ((tid & j) == 0));
            v = takeMax ? (v > p ? v : p) : (v > p ? p : v);
        }
    }
    __syncthreads();

    // ---- unpack rank-tid candidate into SoA; slots 400..447 zero-pad ----
    float4 mybox = make_float4(0.f, 0.f, 0.f, 0.f);
    float myval = -1.0f;
    if (tid < 448) {
        if (tid < WPRE) {
            myval = key_f32((u32)(v >> 32));
            int p = (int)(~(u32)v);
            mybox = ((const float4*)dec)[(size_t)b * P + p];
        }
        cbox[tid] = mybox;
        ara[tid] = (mybox.z - mybox.x) * (mybox.w - mybox.y);
        u64 mk = __ballot(myval > MIN_SCORE);
        if (lane == 0) validm[tid >> 6] = mk;
    }
    __syncthreads();   // skey region now safe to overwrite as inw

    // ---- IoU matrix: 28 upper-triangle tiles as 16 static units (12 row-sharing
    // pairs + 4 singles), 2 units per wave. Unit tables packed in u64 nibbles
    // (wave-uniform shift lookup -- no indexed local arrays, no scratch).
    {
        const u64 RT  = 0x6420543322111000ull;   // r per unit
        const u64 WAT = 0x6666545342531420ull;   // first column block
        const u64 WBT = 0xFFFF656453642531ull;   // second column block (F = none)
        #pragma unroll
        for (int s = 0; s < 2; ++s) {
            const int ui = wv + s * 8;
            const int sh4 = ui * 4;
            const int r  = (int)((RT  >> sh4) & 15);
            const int wA = (int)((WAT >> sh4) & 15);
            const int wB = (int)((WBT >> sh4) & 15);
            if (wB != 15) iou_tile2<true >(cbox, ara, inw, r, wA, wB, lane);
            else          iou_tile2<false>(cbox, ara, inw, r, wA, wA, lane);
        }
    }
    __syncthreads();

    // ---- single-wave hierarchical scan, zero barriers inside ----
    if (wv == 0) {
        u64 keep[7];
        #pragma unroll
        for (int w2 = 0; w2 < 7; ++w2) {
            bool alive = ((validm[w2] >> lane) & 1ull) != 0;
            #pragma unroll
            for (int r = 0; r < w2; ++r) {
                u64 inr = inw[(w2 * 7 + r) * 64 + lane];
                alive = alive && ((inr & keep[r]) == 0ull);
            }
            u64 in_self = inw[(w2 * 7 + w2) * 64 + lane];
            u64 inmask = in_self & ((1ull << lane) - 1ull);   // only t < lane matter
            u64 mm = inmask;
            #pragma unroll
            for (int off = 32; off; off >>= 1) mm |= __shfl_xor(mm, off, 64);
            while (mm) {                        // iterate only suppressing rows
                int t = __builtin_ctzll(mm);
                mm &= mm - 1ull;
                u64 am = __ballot(alive);
                if ((am >> t) & 1ull)
                    alive = alive && (((inmask >> t) & 1ull) == 0ull);
            }
            u64 fin = __ballot(alive);
            keep[w2] = fin;
            if (lane == 0) keepm[w2] = fin;
        }
    }
    __syncthreads();

    if (tid < WPRE) {
        bool keep = (keepm[tid >> 6] >> (tid & 63)) & 1ull;
        cand_sc[((size_t)(b * NC + c)) * WPRE + tid] = keep ? myval : -1.0f;
        ((float4*)cand_bx)[((size_t)(b * NC + c)) * WPRE + tid] = mybox;
    }
}

// ---------------- Kernel 3a: per (image, class-group) exact top-200 ----------------
__global__ __launch_bounds__(512) void topkA_kernel(
    const float* __restrict__ cand_sc, u64* __restrict__ wsA,
    int NC, int TOPK, int GS, int NG)
{
    const int g = blockIdx.x, b = blockIdx.y;
    const int tid = threadIdx.x;
    const int T = 512;
    const int N = GS;                 // 3200
    const u32 fbase = (u32)(g * GS);

    __shared__ u32 hist[1024];
    __shared__ SelSt st;
    __shared__ int sh_cnt;

    const float* s = cand_sc + (size_t)b * NC * WPRE + (size_t)g * GS;
    u64* outg = wsA + (size_t)(b * NG + g) * 256;

    if (tid == 0) sh_cnt = 0;
    __syncthreads();

    hist_select64<512>([&](int i, u64& k) {
                           k = ((u64)f32_key(s[i]) << 32) | (u64)(u32)(~(fbase + (u32)i));
                           return true;
                       },
                       N, TOPK, 256, ((u64)INV32) << 32, tid, hist, &st);
    const u64 thr = st.thr;

    for (int i = tid; i < N; i += T) {
        u64 k = ((u64)f32_key(s[i]) << 32) | (u64)(u32)(~(fbase + (u32)i));
        if (k >= thr) {
            int pos = atomicAdd(&sh_cnt, 1);
            if (pos < 256) outg[pos] = k;
        }
    }
    __syncthreads();
    int cnt = sh_cnt;   // in [TOPK, 256]
    if (tid < 256 && tid >= cnt) outg[tid] = 0ull;
}

// ---------------- Kernel 3b: merge groups, exact top-200, emit ----------------
__global__ __launch_bounds__(256) void topkB_kernel(
    const u64* __restrict__ wsA, const float* __restrict__ cand_bx,
    float* __restrict__ out, int NC, int TOPK, int B, int NG)
{
    const int b = blockIdx.x;
    const int tid = threadIdx.x;
    const int T = 256;
    const int N = NG * 256;           // 2560

    __shared__ u64 keys[2560];
    __shared__ u32 hist[1024];        // cand[256] aliases hist (dead at compaction)
    u64* cand = (u64*)hist;
    __shared__ SelSt st;
    __shared__ int sh_cnt;

    const u64* src = wsA + (size_t)b * N;
    for (int i = tid; i < N; i += T) keys[i] = src[i];
    if (tid == 0) sh_cnt = 0;
    __syncthreads();

    hist_select64<256>([&](int i, u64& k) { k = keys[i]; return true; },
                       N, TOPK, 256, ((u64)INV32) << 32, tid, hist, &st);
    const u64 thr = st.thr;

    for (int i = tid; i < N; i += T) {
        u64 k = keys[i];
        if (k >= thr) {
            int pos = atomicAdd(&sh_cnt, 1);
            if (pos < 256) cand[pos] = k;
        }
    }
    __syncthreads();
    int cnt = sh_cnt;
    u64 v = (tid < cnt) ? cand[tid] : 0ull;

    // register bitonic sort 256 desc (full u64 -> exact (score, flat) order)
    for (int k = 2; k <= 256; k <<= 1) {
        for (int j = k >> 1; j > 0; j >>= 1) {
            u64 p;
            if (j < 64) {
                p = __shfl_xor(v, j, 64);
            } else {
                __syncthreads();
                cand[tid] = v;
                __syncthreads();
                p = cand[tid ^ j];
            }
            bool takeMax = (((tid & k) == 0) == ((tid & j) == 0));
            v = takeMax ? (v > p ? v : p) : (v > p ? p : v);
        }
    }

    if (tid < TOPK) {
        float sc = key_f32((u32)(v >> 32));
        int flat = (int)(~(u32)v);
        int cls = flat / WPRE;
        float4 bx = ((const float4*)cand_bx)[(size_t)b * NC * WPRE + flat];
        float* ob = out + ((size_t)(b * TOPK + tid)) * 4;
        ob[0] = bx.x; ob[1] = bx.y; ob[2] = bx.z; ob[3] = bx.w;
        out[(size_t)B * TOPK * 4 + (size_t)b * TOPK + tid] = (float)(cls + 1);
        out[(size_t)B * TOPK * 5 + (size_t)b * TOPK + tid] = sc;
    }
}

extern "C" void kernel_launch(void* const* d_in, const int* in_sizes, int n_in,
                              void* d_out, int out_size, void* d_ws, size_t ws_size,
                              hipStream_t stream) {
    const float* locs   = (const float*)d_in[0];
    const float* scores = (const float*)d_in[1];
    const float* priors = (const float*)d_in[2];

    const int P  = in_sizes[2] / 4;          // 8732
    const int B  = in_sizes[0] / (4 * P);    // 8
    const int C  = in_sizes[1] / (B * P);    // 81
    const int NC = C - 1;                    // 80
    const int TOPK = out_size / (B * 6);     // 200
    const int NG = 10;                       // class groups per image
    const int GS = (NC * WPRE) / NG;         // 3200 entries per group

    float* ws      = (float*)d_ws;
    float* dec     = ws;                                    // B*P*4
    float* probs_t = dec + (size_t)B * P * 4;               // B*NC*P
    float* cand_sc = probs_t + (size_t)B * NC * P;          // B*NC*WPRE
    float* cand_bx = cand_sc + (size_t)B * NC * WPRE;       // B*NC*WPRE*4
    u64*   wsA     = (u64*)(cand_bx + (size_t)B * NC * WPRE * 4);  // B*NG*256 u64

    dim3 g1((P + 63) / 64, B);
    decode_softmax_kernel<<<g1, 256, 0, stream>>>(locs, scores, priors, dec, probs_t, P, C, NC);

    dim3 g2(NC, B);
    select_nms_kernel<<<g2, 512, 0, stream>>>(dec, probs_t, cand_sc, cand_bx, P, NC);

    dim3 g3(NG, B);
    topkA_kernel<<<g3, 512, 0, stream>>>(cand_sc, wsA, NC, TOPK, GS, NG);
    topkB_kernel<<<dim3(B), 256, 0, stream>>>(wsA, cand_bx, (float*)d_out, NC, TOPK, B, NG);
}

// Round 12
// 141.709 us; speedup vs baseline: 1.5635x; 1.2127x over previous
//
#include <hip/hip_runtime.h>
#include <cstdint>

typedef unsigned long long u64;
typedef unsigned int u32;

#define WPRE 400
#define MIN_SCORE 0.01f
#define MAX_OVERLAP 0.45f
#define INV32 0x407FFFFFu   // f32_key(-1.0f)

// Exact predicate: fdiv_rn(inter,uniC) > 0.45f  <=>  (double)inter > MID*(double)uniC
// MID = midpoint(0.45f, nextafterf(0.45f,+inf)) = 0x1.CCCCCDp-2 (exact double).
#define IOU_MID 0x1.CCCCCDp-2

__device__ __forceinline__ u32 f32_key(float f) {
    u32 u = __float_as_uint(f);
    return (f >= 0.0f) ? (u | 0x80000000u) : ~u;
}
__device__ __forceinline__ float key_f32(u32 k) {
    return __uint_as_float((k & 0x80000000u) ? (k ^ 0x80000000u) : ~k);
}

struct SelSt {
    u64 prefix, thr;
    int r, above, shift, nge, done;
    u32 wtot[8];
};

// Exact top-K threshold over unique u64 keys (descending) via 1024-bin
// histogram level-descent. On return: st->thr such that
// count(keys >= thr) == st->nge, K <= nge <= CAP. Keys must be unique.
// bulk: a key value whose bits [63:14] are shared by a large clump of keys
// (they are register-counted, one LDS atomic per wave per pass); 0 disables.
template <int T, typename KF>
__device__ void hist_select64(KF kf, int N, int K, int CAP, u64 bulk,
                              int tid, u32* hist, SelSt* st)
{
    const int lane = tid & 63;
    const int wv = tid >> 6;
    const int nw = T >> 6;
    constexpr int BPT = 1024 / T;

    if (tid == 0) { st->prefix = 0ull; st->r = K; st->above = 0; st->shift = 54; st->done = 0; }
    __syncthreads();

    while (true) {
        const int shift = st->shift;
        const u64 pref = st->prefix;
        const int r = st->r;
        const int above = st->above;
        const bool lvl0 = (shift == 54);
        #pragma unroll
        for (int q = 0; q < BPT; ++q) hist[tid * BPT + q] = 0u;
        __syncthreads();

        const bool useBulk = (bulk != 0ull) && (shift >= 14);
        const u64 bulkHi = bulk >> 14;
        u32 bulkCnt = 0;
        for (int i = tid; i < N; i += T) {
            u64 k;
            if (!kf(i, k)) continue;
            if (!lvl0 && (k >> (shift + 10)) != pref) continue;
            if (useBulk && (k >> 14) == bulkHi) { ++bulkCnt; continue; }
            atomicAdd(&hist[(u32)(k >> shift) & 1023u], 1u);
        }
        if (useBulk) {
            #pragma unroll
            for (int off = 32; off > 0; off >>= 1) bulkCnt += __shfl_down(bulkCnt, off, 64);
            if (lane == 0 && bulkCnt) atomicAdd(&hist[(u32)(bulk >> shift) & 1023u], bulkCnt);
        }
        __syncthreads();

        // block suffix-scan over 1024 bins (thread t owns bins [t*BPT, ...))
        u32 hloc[BPT], Sarr[BPT];
        u32 run = 0;
        #pragma unroll
        for (int q = BPT - 1; q >= 0; --q) {
            hloc[q] = hist[tid * BPT + q];
            run += hloc[q];
            Sarr[q] = run;
        }
        u32 incl = run;
        #pragma unroll
        for (int off = 1; off < 64; off <<= 1) {
            u32 x = __shfl_down(incl, off, 64);
            incl += (lane + off < 64) ? x : 0u;
        }
        if (lane == 0) st->wtot[wv] = incl;
        __syncthreads();
        u32 wa = 0;
        for (int w2 = wv + 1; w2 < nw; ++w2) wa += st->wtot[w2];
        const u32 suffAbove = wa + (incl - run);

        bool found = false; int fb = 0; u32 fSn = 0, fh = 0;
        #pragma unroll
        for (int q = 0; q < BPT; ++q) {
            u32 S = suffAbove + Sarr[q];
            u32 Sn = S - hloc[q];
            if ((int)S >= r && (int)Sn < r) { found = true; fb = tid * BPT + q; fSn = Sn; fh = hloc[q]; }
        }
        __syncthreads();
        if (found) {
            u64 np = (pref << 10) | (u64)(u32)fb;
            int nab = above + (int)fSn;
            int nge = nab + (int)fh;
            st->prefix = np;
            st->r = r - (int)fSn;
            st->above = nab;
            st->nge = nge;
            st->thr = np << shift;
            st->shift = shift - 10;
            st->done = (nge <= CAP) || (shift == 4);
        }
        __syncthreads();
        if (st->done) break;
    }
}

// ---------------- Kernel 1: decode boxes + softmax ----------------
__global__ __launch_bounds__(256) void decode_softmax_kernel(
    const float* __restrict__ locs, const float* __restrict__ scores,
    const float* __restrict__ priors, float* __restrict__ dec,
    float* __restrict__ probs_t, int P, int C, int NC)
{
    __shared__ float tile[64 * 81];
    __shared__ float mrow[64], srow[64];
    const int b  = blockIdx.y;
    const int p0 = blockIdx.x * 64;
    const int tid = threadIdx.x;
    const int nrows = min(64, P - p0);
    const int n = nrows * C;

    const float* src = scores + ((size_t)b * P + p0) * C;
    for (int idx = tid; idx < n; idx += 256) tile[idx] = src[idx];

    if (tid < nrows) {
        int p = p0 + tid;
        float4 lc = ((const float4*)locs)[(size_t)b * P + p];
        float4 pr = ((const float4*)priors)[p];
        float cx = lc.x * pr.z / 10.0f + pr.x;
        float cy = lc.y * pr.w / 10.0f + pr.y;
        float w  = expf(lc.z / 5.0f) * pr.z;
        float h  = expf(lc.w / 5.0f) * pr.w;
        ((float4*)dec)[(size_t)b * P + p] =
            make_float4(cx - w * 0.5f, cy - h * 0.5f, cx + w * 0.5f, cy + h * 0.5f);
    }
    __syncthreads();

    if (tid < nrows) {
        const float* row = &tile[tid * C];
        float m = row[0];
        for (int cc = 1; cc < C; ++cc) m = fmaxf(m, row[cc]);
        float ss = 0.f;
        for (int cc = 0; cc < C; ++cc) ss += expf(row[cc] - m);
        mrow[tid] = m; srow[tid] = ss;
    }
    __syncthreads();

    for (int idx = tid; idx < 64 * NC; idx += 256) {
        int r  = idx & 63;
        int cc = idx >> 6;
        if (r < nrows) {
            float v = expf(tile[r * C + cc + 1] - mrow[r]) / srow[r];
            probs_t[((size_t)(b * NC + cc)) * P + p0 + r] = v;
        }
    }
}

// ------- Kernel 2: fused per (class,image) top-400 select + sort + IoU + NMS scan -------
// LDS layout: bufA holds skey (34944 B) in phase 1; after skey dies it holds
// inw [0,25088) + cbox [25088,32256) + ara [32256,34048). Total LDS ~39.3 KB
// -> 4 blocks/CU (vs 3 at round 9's 48.6 KB). All compute loops are byte-
// identical to the proven 141 us version (rounds 10/11 lesson: don't touch them).
__global__ __launch_bounds__(512) void select_nms_kernel(
    const float* __restrict__ dec, const float* __restrict__ probs_t,
    float* __restrict__ cand_sc, float* __restrict__ cand_bx,
    int P, int NC)
{
    const int c = blockIdx.x, b = blockIdx.y;
    const int tid = threadIdx.x;
    const int lane = tid & 63;
    const int wv = tid >> 6;
    const int T = 512;

    __shared__ alignas(16) char bufA[8736 * 4];
    u32* skey = (u32*)bufA;
    u64* inw  = (u64*)bufA;                       // [w][r][lane] column words, [0, 25088)
    float4* cbox = (float4*)(bufA + 25088);       // 448 * 16 B = [25088, 32256)
    float*  ara  = (float*)(bufA + 32256);        // 448 * 4 B  = [32256, 34048)
    __shared__ u64 cand[512];                     // hist[1024] aliases cand (dead until compaction)
    u32* hist = (u32*)cand;
    __shared__ u64 validm[7], keepm[7];
    __shared__ SelSt st;
    __shared__ int sh_cnt;

    const float* ps = probs_t + ((size_t)(b * NC + c)) * P;

    // ---- stage masked sortable keys to LDS (vectorized) ----
    int P4 = P >> 2;
    for (int i = tid; i < P4; i += T) {
        float4 f4 = ((const float4*)ps)[i];
        skey[i*4+0] = f32_key(f4.x > MIN_SCORE ? f4.x : -1.0f);
        skey[i*4+1] = f32_key(f4.y > MIN_SCORE ? f4.y : -1.0f);
        skey[i*4+2] = f32_key(f4.z > MIN_SCORE ? f4.z : -1.0f);
        skey[i*4+3] = f32_key(f4.w > MIN_SCORE ? f4.w : -1.0f);
    }
    for (int i = (P4 << 2) + tid; i < P; i += T) {
        float f = ps[i];
        skey[i] = f32_key(f > MIN_SCORE ? f : -1.0f);
    }
    if (tid == 0) sh_cnt = 0;
    __syncthreads();

    // ---- exact top-400 threshold ----
    hist_select64<512>([&](int i, u64& k) {
                           k = ((u64)skey[i] << 32) | (u64)(u32)(~(u32)i);
                           return true;
                       },
                       P, WPRE, 512, ((u64)INV32) << 32, tid, hist, &st);
    const u64 thr = st.thr;

    // ---- compact keys >= thr (count == st.nge <= 512) ----
    for (int i = tid; i < P; i += T) {
        u64 k = ((u64)skey[i] << 32) | (u64)(u32)(~(u32)i);
        if (k >= thr) {
            int pos = atomicAdd(&sh_cnt, 1);
            if (pos < 512) cand[pos] = k;
        }
    }
    __syncthreads();                    // last read of skey is above
    const int cnt = sh_cnt;             // in [400, 512]
    u64 v = (tid < cnt) ? cand[tid] : 0ull;

    // ---- register bitonic sort 512 desc: shfl within wave, LDS for j>=64 ----
    for (int k = 2; k <= 512; k <<= 1) {
        for (int j = k >> 1; j > 0; j >>= 1) {
            u64 p;
            if (j < 64) {
                p = __shfl_xor(v, j, 64);
            } else {
                __syncthreads();
                cand[tid] = v;
                __syncthreads();
                p = cand[tid ^ j];
            }
            bool takeMax = (((tid & k) == 0) == ((tid & j) == 0));
            v = takeMax ? (v > p ? v : p) : (v > p ? p : v);
        }
    }
    __syncthreads();

    // ---- unpack rank-tid candidate into SoA (skey region is dead) ----
    float4 mybox = make_float4(0.f, 0.f, 0.f, 0.f);
    float myval = -1.0f;
    if (tid < 448) {
        if (tid < WPRE) {
            myval = key_f32((u32)(v >> 32));
            int p = (int)(~(u32)v);
            mybox = ((const float4*)dec)[(size_t)b * P + p];
        }
        cbox[tid] = mybox;
        ara[tid] = (mybox.z - mybox.x) * (mybox.w - mybox.y);
        u64 mk = __ballot(myval > MIN_SCORE);
        if (lane == 0) validm[tid >> 6] = mk;
    }
    __syncthreads();

    // ---- column-word IoU matrix: 28 upper-triangle tiles balanced over 8 waves ----
    for (int tt = wv; tt < 28; tt += 8) {
        int r = 0, base = 0;
        while (tt - base >= 7 - r) { base += 7 - r; ++r; }
        int w = r + (tt - base);
        int j = (w << 6) + lane;
        float4 bj = cbox[j];
        float aj = ara[j];
        const int i0 = r << 6;
        u32 acc0 = 0u, acc1 = 0u;
        #pragma unroll 16
        for (int q = 0; q < 32; ++q) {
            int i = i0 + q;
            float4 bi = cbox[i];
            float ai = ara[i];
            float lx = fmaxf(bi.x, bj.x);
            float ly = fmaxf(bi.y, bj.y);
            float rx = fminf(bi.z, bj.z);
            float ry = fminf(bi.w, bj.w);
            float ww = fmaxf(rx - lx, 0.f);
            float hh = fmaxf(ry - ly, 0.f);
            float inter = ww * hh;
            float uniC = fmaxf((ai + aj) - inter, 1e-10f);
            bool pred = (double)inter > IOU_MID * (double)uniC;
            acc0 |= pred ? (1u << q) : 0u;
        }
        #pragma unroll 16
        for (int q = 0; q < 32; ++q) {
            int i = i0 + 32 + q;
            float4 bi = cbox[i];
            float ai = ara[i];
            float lx = fmaxf(bi.x, bj.x);
            float ly = fmaxf(bi.y, bj.y);
            float rx = fminf(bi.z, bj.z);
            float ry = fminf(bi.w, bj.w);
            float ww = fmaxf(rx - lx, 0.f);
            float hh = fmaxf(ry - ly, 0.f);
            float inter = ww * hh;
            float uniC = fmaxf((ai + aj) - inter, 1e-10f);
            bool pred = (double)inter > IOU_MID * (double)uniC;
            acc1 |= pred ? (1u << q) : 0u;
        }
        inw[(w * 7 + r) * 64 + lane] = ((u64)acc1 << 32) | acc0;
    }
    __syncthreads();

    // ---- single-wave hierarchical scan, zero barriers inside ----
    if (wv == 0) {
        u64 keep[7];
        #pragma unroll
        for (int w2 = 0; w2 < 7; ++w2) {
            bool alive = ((validm[w2] >> lane) & 1ull) != 0;
            #pragma unroll
            for (int r = 0; r < w2; ++r) {
                u64 inr = inw[(w2 * 7 + r) * 64 + lane];
                alive = alive && ((inr & keep[r]) == 0ull);
            }
            u64 in_self = inw[(w2 * 7 + w2) * 64 + lane];
            u64 inmask = in_self & ((1ull << lane) - 1ull);   // only t < lane matter
            u64 mm = inmask;
            #pragma unroll
            for (int off = 32; off; off >>= 1) mm |= __shfl_xor(mm, off, 64);
            while (mm) {                        // iterate only suppressing rows
                int t = __builtin_ctzll(mm);
                mm &= mm - 1ull;
                u64 am = __ballot(alive);
                if ((am >> t) & 1ull)
                    alive = alive && (((inmask >> t) & 1ull) == 0ull);
            }
            u64 fin = __ballot(alive);
            keep[w2] = fin;
            if (lane == 0) keepm[w2] = fin;
        }
    }
    __syncthreads();

    if (tid < WPRE) {
        bool keep = (keepm[tid >> 6] >> (tid & 63)) & 1ull;
        cand_sc[((size_t)(b * NC + c)) * WPRE + tid] = keep ? myval : -1.0f;
        ((float4*)cand_bx)[((size_t)(b * NC + c)) * WPRE + tid] = mybox;
    }
}

// ---------------- Kernel 3a: per (image, class-group) exact top-200 ----------------
__global__ __launch_bounds__(512) void topkA_kernel(
    const float* __restrict__ cand_sc, u64* __restrict__ wsA,
    int NC, int TOPK, int GS, int NG)
{
    const int g = blockIdx.x, b = blockIdx.y;
    const int tid = threadIdx.x;
    const int T = 512;
    const int N = GS;                 // 3200
    const u32 fbase = (u32)(g * GS);

    __shared__ u32 hist[1024];
    __shared__ SelSt st;
    __shared__ int sh_cnt;

    const float* s = cand_sc + (size_t)b * NC * WPRE + (size_t)g * GS;
    u64* outg = wsA + (size_t)(b * NG + g) * 256;

    if (tid == 0) sh_cnt = 0;
    __syncthreads();

    hist_select64<512>([&](int i, u64& k) {
                           k = ((u64)f32_key(s[i]) << 32) | (u64)(u32)(~(fbase + (u32)i));
                           return true;
                       },
                       N, TOPK, 256, ((u64)INV32) << 32, tid, hist, &st);
    const u64 thr = st.thr;

    for (int i = tid; i < N; i += T) {
        u64 k = ((u64)f32_key(s[i]) << 32) | (u64)(u32)(~(fbase + (u32)i));
        if (k >= thr) {
            int pos = atomicAdd(&sh_cnt, 1);
            if (pos < 256) outg[pos] = k;
        }
    }
    __syncthreads();
    int cnt = sh_cnt;   // in [TOPK, 256]
    if (tid < 256 && tid >= cnt) outg[tid] = 0ull;
}

// ---------------- Kernel 3b: merge groups, exact top-200, emit ----------------
__global__ __launch_bounds__(256) void topkB_kernel(
    const u64* __restrict__ wsA, const float* __restrict__ cand_bx,
    float* __restrict__ out, int NC, int TOPK, int B, int NG)
{
    const int b = blockIdx.x;
    const int tid = threadIdx.x;
    const int T = 256;
    const int N = NG * 256;           // 2560

    __shared__ u64 keys[2560];
    __shared__ u32 hist[1024];        // cand[256] aliases hist (dead at compaction)
    u64* cand = (u64*)hist;
    __shared__ SelSt st;
    __shared__ int sh_cnt;

    const u64* src = wsA + (size_t)b * N;
    for (int i = tid; i < N; i += T) keys[i] = src[i];
    if (tid == 0) sh_cnt = 0;
    __syncthreads();

    hist_select64<256>([&](int i, u64& k) { k = keys[i]; return true; },
                       N, TOPK, 256, ((u64)INV32) << 32, tid, hist, &st);
    const u64 thr = st.thr;

    for (int i = tid; i < N; i += T) {
        u64 k = keys[i];
        if (k >= thr) {
            int pos = atomicAdd(&sh_cnt, 1);
            if (pos < 256) cand[pos] = k;
        }
    }
    __syncthreads();
    int cnt = sh_cnt;
    u64 v = (tid < cnt) ? cand[tid] : 0ull;

    // register bitonic sort 256 desc (full u64 -> exact (score, flat) order)
    for (int k = 2; k <= 256; k <<= 1) {
        for (int j = k >> 1; j > 0; j >>= 1) {
            u64 p;
            if (j < 64) {
                p = __shfl_xor(v, j, 64);
            } else {
                __syncthreads();
                cand[tid] = v;
                __syncthreads();
                p = cand[tid ^ j];
            }
            bool takeMax = (((tid & k) == 0) == ((tid & j) == 0));
            v = takeMax ? (v > p ? v : p) : (v > p ? p : v);
        }
    }

    if (tid < TOPK) {
        float sc = key_f32((u32)(v >> 32));
        int flat = (int)(~(u32)v);
        int cls = flat / WPRE;
        float4 bx = ((const float4*)cand_bx)[(size_t)b * NC * WPRE + flat];
        float* ob = out + ((size_t)(b * TOPK + tid)) * 4;
        ob[0] = bx.x; ob[1] = bx.y; ob[2] = bx.z; ob[3] = bx.w;
        out[(size_t)B * TOPK * 4 + (size_t)b * TOPK + tid] = (float)(cls + 1);
        out[(size_t)B * TOPK * 5 + (size_t)b * TOPK + tid] = sc;
    }
}

extern "C" void kernel_launch(void* const* d_in, const int* in_sizes, int n_in,
                              void* d_out, int out_size, void* d_ws, size_t ws_size,
                              hipStream_t stream) {
    const float* locs   = (const float*)d_in[0];
    const float* scores = (const float*)d_in[1];
    const float* priors = (const float*)d_in[2];

    const int P  = in_sizes[2] / 4;          // 8732
    const int B  = in_sizes[0] / (4 * P);    // 8
    const int C  = in_sizes[1] / (B * P);    // 81
    const int NC = C - 1;                    // 80
    const int TOPK = out_size / (B * 6);     // 200
    const int NG = 10;                       // class groups per image
    const int GS = (NC * WPRE) / NG;         // 3200 entries per group

    float* ws      = (float*)d_ws;
    float* dec     = ws;                                    // B*P*4
    float* probs_t = dec + (size_t)B * P * 4;               // B*NC*P
    float* cand_sc = probs_t + (size_t)B * NC * P;          // B*NC*WPRE
    float* cand_bx = cand_sc + (size_t)B * NC * WPRE;       // B*NC*WPRE*4
    u64*   wsA     = (u64*)(cand_bx + (size_t)B * NC * WPRE * 4);  // B*NG*256 u64

    dim3 g1((P + 63) / 64, B);
    decode_softmax_kernel<<<g1, 256, 0, stream>>>(locs, scores, priors, dec, probs_t, P, C, NC);

    dim3 g2(NC, B);
    select_nms_kernel<<<g2, 512, 0, stream>>>(dec, probs_t, cand_sc, cand_bx, P, NC);

    dim3 g3(NG, B);
    topkA_kernel<<<g3, 512, 0, stream>>>(cand_sc, wsA, NC, TOPK, GS, NG);
    topkB_kernel<<<dim3(B), 256, 0, stream>>>(wsA, cand_bx, (float*)d_out, NC, TOPK, B, NG);
}